// Round 3
// baseline (497.237 us; speedup 1.0000x reference)
//
#include <hip/hip_runtime.h>
#include <hip/hip_cooperative_groups.h>
#include <cmath>

namespace cg = cooperative_groups;

#define B 32
#define T 1024
#define CDIM 768
#define D 64
#define SCALE 0.03608439182435161f   // 1/sqrt(768), folded into Wq at prep
#define XSTR 72                      // LDS row stride (ushort): 144B, 16B-aligned

typedef short bf16x8 __attribute__((ext_vector_type(8)));
typedef float f32x4 __attribute__((ext_vector_type(4)));
typedef unsigned short u16x8 __attribute__((ext_vector_type(8)));

__device__ inline ushort f2bf(float f) {
  union { float f; unsigned u; } v{f};
  unsigned r = (v.u + 0x7FFFu + ((v.u >> 16) & 1u)) >> 16;  // RNE
  return (ushort)r;
}

// ===========================================================================
// FUSED single-dispatch pipeline (R3): wt_prep -> grid.sync -> proj ->
// grid.sync -> attn. Rationale: R1/R2 null results + pipe-level accounting
// bound real kernel work at ~30 us vs 180 us measured with two ~59 us fills
// in-window -> ~30 us residual attributed to dispatch boundaries. One
// cooperative launch removes 2 of them. Phase bodies are R2's kernels
// verbatim; SMEM aliased per phase (proj 73.7 KB > attn 45 KB).
// 512 blocks x 512 thr, 73.7 KB LDS -> exactly 2 blk/CU x 256 CU = 512
// co-resident (cooperative requirement satisfied).
// ===========================================================================
__global__ __launch_bounds__(512, 4) void fused(
    const float* __restrict__ x,
    const float* __restrict__ Wq, const float* __restrict__ Wk,
    const float* __restrict__ Wv,
    float* __restrict__ out,
    ushort* __restrict__ qkv,          // ws: [3][B*T][D] bf16
    ushort* __restrict__ Wt)           // ws: [192][CDIM] bf16
{
  __shared__ ushort SMEM[36864];       // 73728 B, aliased per phase
  const int t = threadIdx.x;

  // ---------------- phase 0: Wt prep (blocks 0..191) ----------------
  if (blockIdx.x < 192) {
    const int n = blockIdx.x, sel = n >> 6, col = n & 63;
    const float* W = (sel == 0) ? Wq : (sel == 1) ? Wk : Wv;
    const float sc = (sel == 0) ? SCALE : 1.f;
    for (int k = t; k < CDIM; k += 512)
      Wt[(size_t)n * CDIM + k] = f2bf(W[(size_t)k * D + col] * sc);
  }
  __threadfence();
  cg::this_grid().sync();

  // ---------------- phase 1: QKV projection + RoPE (R2 body) ----------------
  {
    const int lane = t & 63;
    const int wid  = t >> 6;             // 0..7
    const int ln16 = lane & 15;
    const int quad = lane >> 4;
    const int mt   = wid & 3;            // M-tile (16 rows each)
    const int nh   = wid >> 2;           // N-half (6 nt each)
    const int row0 = blockIdx.x * 64;

    ushort* Xs0 = SMEM;                  // [2][64*XSTR]  = 9216 ushorts
    ushort* Ws0 = SMEM + 2 * 64 * XSTR;  // [2][192*XSTR] = 27648 ushorts

    f32x4 acc[6];
    #pragma unroll
    for (int nt = 0; nt < 6; ++nt) acc[nt] = (f32x4){0.f, 0.f, 0.f, 0.f};

    float4 xp[2][2];
    u16x8  wp[2][3];

    auto load_stage = [&](int s, int set) {
      const int k0 = s * 64;
      #pragma unroll
      for (int it = 0; it < 2; ++it) {
        int slot = it * 512 + t, row = slot >> 4, kq = slot & 15;
        xp[set][it] = *(const float4*)(x + (size_t)(row0 + row) * CDIM + k0 + kq * 4);
      }
      #pragma unroll
      for (int it = 0; it < 3; ++it) {
        int slot = it * 512 + t, n = slot >> 3, kb = slot & 7;
        wp[set][it] = *(const u16x8*)(Wt + (size_t)n * CDIM + k0 + kb * 8);
      }
    };

    load_stage(0, 0);
    load_stage(1, 1);
    int buf = 0;
    for (int s = 0; s < CDIM / 64; ++s) {
      const int set = s & 1;
      ushort* Xs = Xs0 + buf * 64 * XSTR;
      ushort* Ws = Ws0 + buf * 192 * XSTR;
      #pragma unroll
      for (int it = 0; it < 2; ++it) {
        int slot = it * 512 + t, row = slot >> 4, kq = slot & 15;
        ushort4 bv;
        bv.x = f2bf(xp[set][it].x); bv.y = f2bf(xp[set][it].y);
        bv.z = f2bf(xp[set][it].z); bv.w = f2bf(xp[set][it].w);
        *(ushort4*)&Xs[row * XSTR + kq * 4] = bv;
      }
      #pragma unroll
      for (int it = 0; it < 3; ++it) {
        int slot = it * 512 + t, n = slot >> 3, kb = slot & 7;
        *(u16x8*)&Ws[n * XSTR + kb * 8] = wp[set][it];
      }
      __syncthreads();
      if (s + 2 < CDIM / 64) load_stage(s + 2, set);

      #pragma unroll
      for (int ks = 0; ks < 2; ++ks) {
        bf16x8 a = *(const bf16x8*)&Xs[(mt * 16 + ln16) * XSTR + ks * 32 + quad * 8];
        #pragma unroll
        for (int nt = 0; nt < 6; ++nt) {
          const int ntg = nh * 6 + nt;
          bf16x8 bb = *(const bf16x8*)&Ws[(ntg * 16 + ln16) * XSTR + ks * 32 + quad * 8];
          acc[nt] = __builtin_amdgcn_mfma_f32_16x16x32_bf16(a, bb, acc[nt], 0, 0, 0);
        }
      }
      __syncthreads();   // protect buf reuse before next stage's LDS writes
      buf ^= 1;
    }

    #pragma unroll
    for (int nt = 0; nt < 6; ++nt) {
      const int ntg = nh * 6 + nt;
      const int sel = ntg >> 2;
      const int d   = (ntg & 3) * 16 + ln16;
      ushort* outb = qkv + (size_t)sel * (B * T * D);
      if (sel < 2) {
        const float freq = __expf((float)(d & 62) * (-0.14391156855801f));
        const float sgn  = (d & 1) ? 1.f : -1.f;
        #pragma unroll
        for (int reg = 0; reg < 4; ++reg) {
          int rowg = row0 + mt * 16 + quad * 4 + reg;
          float s, c;
          __sincosf((float)(rowg & (T - 1)) * freq, &s, &c);
          float val = acc[nt][reg];
          float partner = __shfl_xor(val, 1, 64);
          outb[(size_t)rowg * D + d] = f2bf(fmaf(sgn * partner, s, val * c));
        }
      } else {
        #pragma unroll
        for (int reg = 0; reg < 4; ++reg) {
          int rowg = row0 + mt * 16 + quad * 4 + reg;
          outb[(size_t)rowg * D + d] = f2bf(acc[nt][reg]);
        }
      }
    }
  }
  __threadfence();
  cg::this_grid().sync();

  // ---------------- phase 2: causal flash attention (R1 body) ----------------
  // Waves 0..3 active; waves 4..7 participate in barriers only (uniform trip
  // count per block). s_setprio(1) wraps MFMA clusters (m191: attn-positive
  // with independent co-resident blocks).
  {
    const bool act = t < 256;
    const int lane = t & 63;
    const int wid  = t >> 6;             // active: 0..3
    const int ln16 = lane & 15;
    const int quad = lane >> 4;
    const int l    = (int)blockIdx.x;    // 0..511
    const int b    = l & 31;             // XCD = l%8 = b%8 -> K/V L2-resident
    const int r    = l >> 5;
    const int qt   = (r < 8) ? r : 23 - r;  // cohabitants sum to 17 units

    ushort* Ks0 = SMEM;                  // [2][64*XSTR]
    ushort* Vt0 = SMEM + 2 * 64 * XSTR;  // [2][64*XSTR]
    ushort* Pl  = SMEM + 4 * 64 * XSTR;  // [64*XSTR] wave-private rows

    const ushort* qg = qkv;
    const ushort* kg = qkv + (size_t)B * T * D;
    const ushort* vg = qkv + 2 * (size_t)B * T * D;

    bf16x8 qf[2];
    if (act) {
      const ushort* qrow = qg + (size_t)(b * T + qt * 64 + wid * 16 + ln16) * D;
      qf[0] = *(const bf16x8*)(qrow + quad * 8);
      qf[1] = *(const bf16x8*)(qrow + quad * 8 + 32);
    }

    f32x4 O[4];
    #pragma unroll
    for (int nt = 0; nt < 4; ++nt) O[nt] = (f32x4){0.f, 0.f, 0.f, 0.f};
    float l_sum = 0.f;

    const int kb = t & 15, db = t >> 4;
    const int d0 = (db & 15) * 4, kk0 = kb * 4;

    u16x8  kp[2];
    ushort4 vp[4];
    auto load_kv = [&](int kt) {
      #pragma unroll
      for (int i = 0; i < 2; ++i) {
        int slot = i * 256 + t, row = slot >> 3, dblk = slot & 7;
        kp[i] = *(const u16x8*)(kg + (size_t)(b * T + kt * 64 + row) * D + dblk * 8);
      }
      #pragma unroll
      for (int i = 0; i < 4; ++i)
        vp[i] = *(const ushort4*)(vg + (size_t)(b * T + kt * 64 + kk0 + i) * D + d0);
    };

    if (act) load_kv(0);
    int buf = 0;
    for (int kt = 0; kt <= qt; ++kt) {
      ushort* Ks = Ks0 + buf * 64 * XSTR;
      ushort* Vt = Vt0 + buf * 64 * XSTR;
      if (act) {
        #pragma unroll
        for (int i = 0; i < 2; ++i) {
          int slot = i * 256 + t, row = slot >> 3, dblk = slot & 7;
          *(u16x8*)&Ks[row * XSTR + dblk * 8] = kp[i];
        }
        const ushort* vpe = (const ushort*)vp;
        #pragma unroll
        for (int j = 0; j < 4; ++j) {
          ushort4 c;
          c.x = vpe[0 * 4 + j]; c.y = vpe[1 * 4 + j];
          c.z = vpe[2 * 4 + j]; c.w = vpe[3 * 4 + j];
          *(ushort4*)&Vt[(d0 + j) * XSTR + kk0] = c;
        }
      }
      __syncthreads();
      if (act) {
        if (kt < qt) load_kv(kt + 1);

        // --- S^T[key][q] = K.Q^T ---
        f32x4 s[4];
        #pragma unroll
        for (int mt = 0; mt < 4; ++mt) s[mt] = (f32x4){0.f, 0.f, 0.f, 0.f};
        __builtin_amdgcn_s_setprio(1);
        #pragma unroll
        for (int ks = 0; ks < 2; ++ks)
          #pragma unroll
          for (int mt = 0; mt < 4; ++mt) {
            bf16x8 kf = *(const bf16x8*)&Ks[(mt * 16 + ln16) * XSTR + quad * 8 + ks * 32];
            s[mt] = __builtin_amdgcn_mfma_f32_16x16x32_bf16(kf, qf[ks], s[mt], 0, 0, 0);
          }
        __builtin_amdgcn_s_setprio(0);

        if (kt == qt) {              // causal mask: exp(-1e30) flushes to 0
          const int ql = wid * 16 + ln16;
          #pragma unroll
          for (int mt = 0; mt < 4; ++mt)
            #pragma unroll
            for (int reg = 0; reg < 4; ++reg)
              if (mt * 16 + quad * 4 + reg > ql) s[mt][reg] = -1e30f;
        }

        // --- static softmax: P = exp(s) (scores bounded, no max needed) ---
        float psum = 0.f;
        #pragma unroll
        for (int mt = 0; mt < 4; ++mt) {
          float p0 = __expf(s[mt][0]), p1 = __expf(s[mt][1]);
          float p2 = __expf(s[mt][2]), p3 = __expf(s[mt][3]);
          psum += (p0 + p1) + (p2 + p3);
          ushort4 pk;
          pk.x = f2bf(p0); pk.y = f2bf(p1); pk.z = f2bf(p2); pk.w = f2bf(p3);
          *(ushort4*)&Pl[(wid * 16 + ln16) * XSTR + mt * 16 + quad * 4] = pk;
        }
        psum += __shfl_xor(psum, 16, 64);
        psum += __shfl_xor(psum, 32, 64);
        l_sum += psum;

        // --- PV: O accumulates, no rescale needed ---
        bf16x8 pa[2];
        pa[0] = *(const bf16x8*)&Pl[(wid * 16 + ln16) * XSTR + quad * 8];
        pa[1] = *(const bf16x8*)&Pl[(wid * 16 + ln16) * XSTR + quad * 8 + 32];
        __builtin_amdgcn_s_setprio(1);
        #pragma unroll
        for (int ks = 0; ks < 2; ++ks)
          #pragma unroll
          for (int nt = 0; nt < 4; ++nt) {
            bf16x8 vf = *(const bf16x8*)&Vt[(nt * 16 + ln16) * XSTR + quad * 8 + ks * 32];
            O[nt] = __builtin_amdgcn_mfma_f32_16x16x32_bf16(pa[ks], vf, O[nt], 0, 0, 0);
          }
        __builtin_amdgcn_s_setprio(0);
      }
      buf ^= 1;
    }

    if (act) {
      float inv = 1.f / l_sum;
      #pragma unroll
      for (int reg = 0; reg < 4; ++reg) {
        float iv = __shfl(inv, quad * 4 + reg, 64);
        size_t row = (size_t)(b * T + qt * 64 + wid * 16 + quad * 4 + reg) * D;
        #pragma unroll
        for (int nt = 0; nt < 4; ++nt)
          out[row + nt * 16 + ln16] = O[nt][reg] * iv;
      }
    }
  }
}

// ===========================================================================
// Fallback 3-kernel path (R2), used if cooperative launch is rejected.
// ===========================================================================
__global__ __launch_bounds__(256) void wt_prep(
    const float* __restrict__ Wq, const float* __restrict__ Wk,
    const float* __restrict__ Wv, ushort* __restrict__ Wt)
{
  const int n   = blockIdx.x;
  const int sel = n >> 6, col = n & 63;
  const float* W = (sel == 0) ? Wq : (sel == 1) ? Wk : Wv;
  const float sc = (sel == 0) ? SCALE : 1.f;
  for (int k = threadIdx.x; k < CDIM; k += 256)
    Wt[(size_t)n * CDIM + k] = f2bf(W[(size_t)k * D + col] * sc);
}

__global__ __launch_bounds__(512, 4) void proj_mfma(
    const float* __restrict__ x,
    const ushort* __restrict__ Wt,
    ushort* __restrict__ qkv)
{
  const int t    = threadIdx.x;
  const int lane = t & 63;
  const int wid  = t >> 6;
  const int ln16 = lane & 15;
  const int quad = lane >> 4;
  const int mt   = wid & 3;
  const int nh   = wid >> 2;
  const int row0 = blockIdx.x * 64;

  __shared__ ushort Xs[2][64 * XSTR];
  __shared__ ushort Ws[2][192 * XSTR];

  f32x4 acc[6];
  #pragma unroll
  for (int nt = 0; nt < 6; ++nt) acc[nt] = (f32x4){0.f, 0.f, 0.f, 0.f};

  float4 xp[2][2];
  u16x8  wp[2][3];

  auto load_stage = [&](int s, int set) {
    const int k0 = s * 64;
    #pragma unroll
    for (int it = 0; it < 2; ++it) {
      int slot = it * 512 + t, row = slot >> 4, kq = slot & 15;
      xp[set][it] = *(const float4*)(x + (size_t)(row0 + row) * CDIM + k0 + kq * 4);
    }
    #pragma unroll
    for (int it = 0; it < 3; ++it) {
      int slot = it * 512 + t, n = slot >> 3, kb = slot & 7;
      wp[set][it] = *(const u16x8*)(Wt + (size_t)n * CDIM + k0 + kb * 8);
    }
  };

  load_stage(0, 0);
  load_stage(1, 1);
  int buf = 0;
  for (int s = 0; s < CDIM / 64; ++s) {
    const int set = s & 1;
    #pragma unroll
    for (int it = 0; it < 2; ++it) {
      int slot = it * 512 + t, row = slot >> 4, kq = slot & 15;
      ushort4 bv;
      bv.x = f2bf(xp[set][it].x); bv.y = f2bf(xp[set][it].y);
      bv.z = f2bf(xp[set][it].z); bv.w = f2bf(xp[set][it].w);
      *(ushort4*)&Xs[buf][row * XSTR + kq * 4] = bv;
    }
    #pragma unroll
    for (int it = 0; it < 3; ++it) {
      int slot = it * 512 + t, n = slot >> 3, kb = slot & 7;
      *(u16x8*)&Ws[buf][n * XSTR + kb * 8] = wp[set][it];
    }
    __syncthreads();
    if (s + 2 < CDIM / 64) load_stage(s + 2, set);

    #pragma unroll
    for (int ks = 0; ks < 2; ++ks) {
      bf16x8 a = *(const bf16x8*)&Xs[buf][(mt * 16 + ln16) * XSTR + ks * 32 + quad * 8];
      #pragma unroll
      for (int nt = 0; nt < 6; ++nt) {
        const int ntg = nh * 6 + nt;
        bf16x8 bb = *(const bf16x8*)&Ws[buf][(ntg * 16 + ln16) * XSTR + ks * 32 + quad * 8];
        acc[nt] = __builtin_amdgcn_mfma_f32_16x16x32_bf16(a, bb, acc[nt], 0, 0, 0);
      }
    }
    buf ^= 1;
  }

  #pragma unroll
  for (int nt = 0; nt < 6; ++nt) {
    const int ntg = nh * 6 + nt;
    const int sel = ntg >> 2;
    const int d   = (ntg & 3) * 16 + ln16;
    ushort* outb = qkv + (size_t)sel * (B * T * D);
    if (sel < 2) {
      const float freq = __expf((float)(d & 62) * (-0.14391156855801f));
      const float sgn  = (d & 1) ? 1.f : -1.f;
      #pragma unroll
      for (int reg = 0; reg < 4; ++reg) {
        int rowg = row0 + mt * 16 + quad * 4 + reg;
        float s, c;
        __sincosf((float)(rowg & (T - 1)) * freq, &s, &c);
        float val = acc[nt][reg];
        float partner = __shfl_xor(val, 1, 64);
        outb[(size_t)rowg * D + d] = f2bf(fmaf(sgn * partner, s, val * c));
      }
    } else {
      #pragma unroll
      for (int reg = 0; reg < 4; ++reg) {
        int rowg = row0 + mt * 16 + quad * 4 + reg;
        outb[(size_t)rowg * D + d] = f2bf(acc[nt][reg]);
      }
    }
  }
}

__global__ __launch_bounds__(256) void attn_mfma(
    const ushort* __restrict__ qg,
    const ushort* __restrict__ kg,
    const ushort* __restrict__ vg,
    float* __restrict__ out)
{
  const int t    = threadIdx.x;
  const int lane = t & 63;
  const int wid  = t >> 6;
  const int ln16 = lane & 15;
  const int quad = lane >> 4;
  const int l    = (int)blockIdx.x;
  const int b    = l & 31;
  const int r    = l >> 5;
  const int qt   = (r < 8) ? r : 23 - r;

  __shared__ ushort Ks[2][64 * XSTR];
  __shared__ ushort Vt[2][64 * XSTR];
  __shared__ ushort Pl[64 * XSTR];

  bf16x8 qf[2];
  {
    const ushort* qrow = qg + (size_t)(b * T + qt * 64 + wid * 16 + ln16) * D;
    qf[0] = *(const bf16x8*)(qrow + quad * 8);
    qf[1] = *(const bf16x8*)(qrow + quad * 8 + 32);
  }

  f32x4 O[4];
  #pragma unroll
  for (int nt = 0; nt < 4; ++nt) O[nt] = (f32x4){0.f, 0.f, 0.f, 0.f};
  float l_sum = 0.f;

  const int kb = t & 15, db = t >> 4;
  const int d0 = db * 4, kk0 = kb * 4;

  u16x8  kp[2];
  ushort4 vp[4];
  auto load_kv = [&](int kt) {
    #pragma unroll
    for (int i = 0; i < 2; ++i) {
      int slot = i * 256 + t, row = slot >> 3, dblk = slot & 7;
      kp[i] = *(const u16x8*)(kg + (size_t)(b * T + kt * 64 + row) * D + dblk * 8);
    }
    #pragma unroll
    for (int i = 0; i < 4; ++i)
      vp[i] = *(const ushort4*)(vg + (size_t)(b * T + kt * 64 + kk0 + i) * D + d0);
  };

  load_kv(0);
  int buf = 0;
  for (int kt = 0; kt <= qt; ++kt) {
    #pragma unroll
    for (int i = 0; i < 2; ++i) {
      int slot = i * 256 + t, row = slot >> 3, dblk = slot & 7;
      *(u16x8*)&Ks[buf][row * XSTR + dblk * 8] = kp[i];
    }
    const ushort* vpe = (const ushort*)vp;
    #pragma unroll
    for (int j = 0; j < 4; ++j) {
      ushort4 c;
      c.x = vpe[0 * 4 + j]; c.y = vpe[1 * 4 + j];
      c.z = vpe[2 * 4 + j]; c.w = vpe[3 * 4 + j];
      *(ushort4*)&Vt[buf][(d0 + j) * XSTR + kk0] = c;
    }
    __syncthreads();
    if (kt < qt) load_kv(kt + 1);

    f32x4 s[4];
    #pragma unroll
    for (int mt = 0; mt < 4; ++mt) s[mt] = (f32x4){0.f, 0.f, 0.f, 0.f};
    #pragma unroll
    for (int ks = 0; ks < 2; ++ks)
      #pragma unroll
      for (int mt = 0; mt < 4; ++mt) {
        bf16x8 kf = *(const bf16x8*)&Ks[buf][(mt * 16 + ln16) * XSTR + quad * 8 + ks * 32];
        s[mt] = __builtin_amdgcn_mfma_f32_16x16x32_bf16(kf, qf[ks], s[mt], 0, 0, 0);
      }

    if (kt == qt) {
      const int ql = wid * 16 + ln16;
      #pragma unroll
      for (int mt = 0; mt < 4; ++mt)
        #pragma unroll
        for (int reg = 0; reg < 4; ++reg)
          if (mt * 16 + quad * 4 + reg > ql) s[mt][reg] = -1e30f;
    }

    float psum = 0.f;
    #pragma unroll
    for (int mt = 0; mt < 4; ++mt) {
      float p0 = __expf(s[mt][0]), p1 = __expf(s[mt][1]);
      float p2 = __expf(s[mt][2]), p3 = __expf(s[mt][3]);
      psum += (p0 + p1) + (p2 + p3);
      ushort4 pk;
      pk.x = f2bf(p0); pk.y = f2bf(p1); pk.z = f2bf(p2); pk.w = f2bf(p3);
      *(ushort4*)&Pl[(wid * 16 + ln16) * XSTR + mt * 16 + quad * 4] = pk;
    }
    psum += __shfl_xor(psum, 16, 64);
    psum += __shfl_xor(psum, 32, 64);
    l_sum += psum;

    bf16x8 pa[2];
    pa[0] = *(const bf16x8*)&Pl[(wid * 16 + ln16) * XSTR + quad * 8];
    pa[1] = *(const bf16x8*)&Pl[(wid * 16 + ln16) * XSTR + quad * 8 + 32];
    #pragma unroll
    for (int ks = 0; ks < 2; ++ks)
      #pragma unroll
      for (int nt = 0; nt < 4; ++nt) {
        bf16x8 vf = *(const bf16x8*)&Vt[buf][(nt * 16 + ln16) * XSTR + quad * 8 + ks * 32];
        O[nt] = __builtin_amdgcn_mfma_f32_16x16x32_bf16(pa[ks], vf, O[nt], 0, 0, 0);
      }
    buf ^= 1;
  }

  float inv = 1.f / l_sum;
  #pragma unroll
  for (int reg = 0; reg < 4; ++reg) {
    float iv = __shfl(inv, quad * 4 + reg, 64);
    size_t row = (size_t)(b * T + qt * 64 + wid * 16 + quad * 4 + reg) * D;
    #pragma unroll
    for (int nt = 0; nt < 4; ++nt)
      out[row + nt * 16 + ln16] = O[nt][reg] * iv;
  }
}

// ---------------------------------------------------------------------------
extern "C" void kernel_launch(void* const* d_in, const int* in_sizes, int n_in,
                              void* d_out, int out_size, void* d_ws, size_t ws_size,
                              hipStream_t stream) {
  const float* x  = (const float*)d_in[0];
  const float* Wq = (const float*)d_in[1];
  const float* Wk = (const float*)d_in[2];
  const float* Wv = (const float*)d_in[3];
  float* outp = (float*)d_out;

  ushort* qkv = (ushort*)d_ws;                         // 12.58 MB bf16
  ushort* Wt  = qkv + (size_t)3 * B * T * D;           // +288 KB bf16

  void* args[] = {(void*)&x, (void*)&Wq, (void*)&Wk, (void*)&Wv,
                  (void*)&outp, (void*)&qkv, (void*)&Wt};
  hipError_t err = hipLaunchCooperativeKernel(
      (void*)fused, dim3(512), dim3(512), args, 0, stream);

  if (err != hipSuccess) {
    // Fallback: 3-dispatch path (R2 behavior).
    wt_prep<<<dim3(192), dim3(256), 0, stream>>>(Wq, Wk, Wv, Wt);
    proj_mfma<<<dim3((B * T) / 64), dim3(512), 0, stream>>>(x, Wt, qkv);
    attn_mfma<<<dim3(T / 64 * B), dim3(256), 0, stream>>>(
        qkv, qkv + (size_t)B * T * D, qkv + 2 * (size_t)B * T * D, outp);
  }
}

// Round 4
// 183.422 us; speedup vs baseline: 2.7109x; 2.7109x over previous
//
#include <hip/hip_runtime.h>
#include <cmath>

#define B 32
#define T 1024
#define CDIM 768
#define D 64
#define SCALE 0.03608439182435161f   // 1/sqrt(768), folded into Wq at prep
#define XSTR 72                      // LDS row stride (ushort): 144B, 16B-aligned

typedef short bf16x8 __attribute__((ext_vector_type(8)));
typedef float f32x4 __attribute__((ext_vector_type(4)));
typedef unsigned short u16x8 __attribute__((ext_vector_type(8)));

__device__ inline ushort f2bf(float f) {
  union { float f; unsigned u; } v{f};
  unsigned r = (v.u + 0x7FFFu + ((v.u >> 16) & 1u)) >> 16;  // RNE
  return (ushort)r;
}

// ---------------------------------------------------------------------------
// Kernel 0: one-time W transpose + bf16 cvt: Wt[n=sel*64+col][k] = W_sel[k][col]
// (Wq pre-scaled by 1/sqrt(768); commutes with RoPE since rotation is linear.)
// ---------------------------------------------------------------------------
__global__ __launch_bounds__(256) void wt_prep(
    const float* __restrict__ Wq, const float* __restrict__ Wk,
    const float* __restrict__ Wv, ushort* __restrict__ Wt)
{
  const int n   = blockIdx.x;          // 0..191
  const int sel = n >> 6, col = n & 63;
  const float* W = (sel == 0) ? Wq : (sel == 1) ? Wk : Wv;
  const float sc = (sel == 0) ? SCALE : 1.f;
  for (int k = threadIdx.x; k < CDIM; k += 256)
    Wt[(size_t)n * CDIM + k] = f2bf(W[(size_t)k * D + col] * sc);
}

// ---------------------------------------------------------------------------
// Kernel 1: fused QKV projection GEMM (N=192) + RoPE, bf16 out.
// R4: R2 structure (512 thr / 8 waves, LDS double-buffer, one barrier/stage,
// 2-deep register prefetch) with ONE change: the prefetch issue for stage s+2
// moves BEFORE the barrier (its register sources are dead once the LDS writes
// complete) — each stage gains the barrier-drain time of latency cover.
// R3 lesson: do NOT co-compile phases into one kernel (regalloc collapse to
// 64 VGPR, 5x regression). R6 lesson: do NOT remove LDS staging.
// ---------------------------------------------------------------------------
__global__ __launch_bounds__(512, 4) void proj_mfma(
    const float* __restrict__ x,
    const ushort* __restrict__ Wt,
    ushort* __restrict__ qkv)          // [3][B*T][D] bf16
{
  const int t    = threadIdx.x;        // 0..511
  const int lane = t & 63;
  const int wid  = t >> 6;             // 0..7
  const int ln16 = lane & 15;
  const int quad = lane >> 4;
  const int mt   = wid & 3;            // M-tile (16 rows each)
  const int nh   = wid >> 2;           // N-half (6 nt each)
  const int row0 = blockIdx.x * 64;

  __shared__ ushort Xs[2][64 * XSTR];    // 2 x 9216 B
  __shared__ ushort Ws[2][192 * XSTR];   // 2 x 27648 B (73.7 KB -> 2 blk/CU)

  f32x4 acc[6];
  #pragma unroll
  for (int nt = 0; nt < 6; ++nt) acc[nt] = (f32x4){0.f, 0.f, 0.f, 0.f};

  float4 xp[2][2];   // 2-deep x prefetch (fp32, cvt at LDS-write time)
  u16x8  wp[2][3];   // 2-deep Wt prefetch (already bf16)

  auto load_stage = [&](int s, int set) {
    const int k0 = s * 64;
    #pragma unroll
    for (int it = 0; it < 2; ++it) {
      int slot = it * 512 + t, row = slot >> 4, kq = slot & 15;
      xp[set][it] = *(const float4*)(x + (size_t)(row0 + row) * CDIM + k0 + kq * 4);
    }
    #pragma unroll
    for (int it = 0; it < 3; ++it) {
      int slot = it * 512 + t, n = slot >> 3, kb = slot & 7;
      wp[set][it] = *(const u16x8*)(Wt + (size_t)n * CDIM + k0 + kb * 8);
    }
  };

  load_stage(0, 0);
  load_stage(1, 1);
  int buf = 0;
  for (int s = 0; s < CDIM / 64; ++s) {
    const int set = s & 1;
    #pragma unroll
    for (int it = 0; it < 2; ++it) {
      int slot = it * 512 + t, row = slot >> 4, kq = slot & 15;
      ushort4 bv;
      bv.x = f2bf(xp[set][it].x); bv.y = f2bf(xp[set][it].y);
      bv.z = f2bf(xp[set][it].z); bv.w = f2bf(xp[set][it].w);
      *(ushort4*)&Xs[buf][row * XSTR + kq * 4] = bv;
    }
    #pragma unroll
    for (int it = 0; it < 3; ++it) {
      int slot = it * 512 + t, n = slot >> 3, kb = slot & 7;
      *(u16x8*)&Ws[buf][n * XSTR + kb * 8] = wp[set][it];
    }
    if (s + 2 < CDIM / 64) load_stage(s + 2, set);   // issue-early: before barrier
    __syncthreads();

    #pragma unroll
    for (int ks = 0; ks < 2; ++ks) {
      bf16x8 a = *(const bf16x8*)&Xs[buf][(mt * 16 + ln16) * XSTR + ks * 32 + quad * 8];
      #pragma unroll
      for (int nt = 0; nt < 6; ++nt) {
        const int ntg = nh * 6 + nt;
        bf16x8 bb = *(const bf16x8*)&Ws[buf][(ntg * 16 + ln16) * XSTR + ks * 32 + quad * 8];
        acc[nt] = __builtin_amdgcn_mfma_f32_16x16x32_bf16(a, bb, acc[nt], 0, 0, 0);
      }
    }
    buf ^= 1;
  }

  // epilogue: C/D col=ln16, row=quad*4+reg; sel = ntg>>2, d = (ntg&3)*16+ln16
  #pragma unroll
  for (int nt = 0; nt < 6; ++nt) {
    const int ntg = nh * 6 + nt;
    const int sel = ntg >> 2;
    const int d   = (ntg & 3) * 16 + ln16;
    ushort* outb = qkv + (size_t)sel * (B * T * D);
    if (sel < 2) {
      const float freq = __expf((float)(d & 62) * (-0.14391156855801f));
      const float sgn  = (d & 1) ? 1.f : -1.f;
      #pragma unroll
      for (int reg = 0; reg < 4; ++reg) {
        int rowg = row0 + mt * 16 + quad * 4 + reg;
        float s, c;
        __sincosf((float)(rowg & (T - 1)) * freq, &s, &c);
        float val = acc[nt][reg];
        float partner = __shfl_xor(val, 1, 64);
        outb[(size_t)rowg * D + d] = f2bf(fmaf(sgn * partner, s, val * c));
      }
    } else {
      #pragma unroll
      for (int reg = 0; reg < 4; ++reg) {
        int rowg = row0 + mt * 16 + quad * 4 + reg;
        outb[(size_t)rowg * D + d] = f2bf(acc[nt][reg]);
      }
    }
  }
}

// ---------------------------------------------------------------------------
// Kernel 2: causal flash attention, bf16 MFMA, STATIC softmax (m == 0).
// Scores statically bounded -> no online-max machinery (shift-invariant).
// S^T = K·Q^T; double-buffered Ks/Vt; one barrier per kt.
// R1 remap kept (balanced CU load, K/V L2-resident per XCD).
// R4: (a) load_kv(kt+1) issued BEFORE the barrier (kp/vp dead after LDS
// writes) — extra latency cover per iter; (b) s_setprio(1) around both MFMA
// clusters (m191: +4-7% for independent co-resident attn blocks).
// ---------------------------------------------------------------------------
__global__ __launch_bounds__(256) void attn_mfma(
    const ushort* __restrict__ qg,
    const ushort* __restrict__ kg,
    const ushort* __restrict__ vg,
    float* __restrict__ out)
{
  const int t    = threadIdx.x;
  const int lane = t & 63;
  const int wid  = t >> 6;
  const int ln16 = lane & 15;
  const int quad = lane >> 4;
  const int l    = (int)blockIdx.x;      // 0..511
  const int b    = l & 31;               // XCD = l%8 = b%8 -> K/V L2-resident
  const int r    = l >> 5;
  const int qt   = (r < 8) ? r : 23 - r; // cohabitant qt's sum to 15

  __shared__ ushort Ks[2][64 * XSTR];
  __shared__ ushort Vt[2][64 * XSTR];
  __shared__ ushort Pl[64 * XSTR];         // wave-private rows

  bf16x8 qf[2];
  {
    const ushort* qrow = qg + (size_t)(b * T + qt * 64 + wid * 16 + ln16) * D;
    qf[0] = *(const bf16x8*)(qrow + quad * 8);
    qf[1] = *(const bf16x8*)(qrow + quad * 8 + 32);
  }

  f32x4 O[4];
  #pragma unroll
  for (int nt = 0; nt < 4; ++nt) O[nt] = (f32x4){0.f, 0.f, 0.f, 0.f};
  float l_sum = 0.f;

  const int kb = t & 15, db = t >> 4;
  const int d0 = db * 4, kk0 = kb * 4;

  u16x8  kp[2];
  ushort4 vp[4];
  auto load_kv = [&](int kt) {
    #pragma unroll
    for (int i = 0; i < 2; ++i) {
      int slot = i * 256 + t, row = slot >> 3, dblk = slot & 7;
      kp[i] = *(const u16x8*)(kg + (size_t)(b * T + kt * 64 + row) * D + dblk * 8);
    }
    #pragma unroll
    for (int i = 0; i < 4; ++i)
      vp[i] = *(const ushort4*)(vg + (size_t)(b * T + kt * 64 + kk0 + i) * D + d0);
  };

  load_kv(0);
  int buf = 0;
  for (int kt = 0; kt <= qt; ++kt) {
    #pragma unroll
    for (int i = 0; i < 2; ++i) {
      int slot = i * 256 + t, row = slot >> 3, dblk = slot & 7;
      *(u16x8*)&Ks[buf][row * XSTR + dblk * 8] = kp[i];
    }
    const ushort* vpe = (const ushort*)vp;
    #pragma unroll
    for (int j = 0; j < 4; ++j) {
      ushort4 c;
      c.x = vpe[0 * 4 + j]; c.y = vpe[1 * 4 + j];
      c.z = vpe[2 * 4 + j]; c.w = vpe[3 * 4 + j];
      *(ushort4*)&Vt[buf][(d0 + j) * XSTR + kk0] = c;
    }
    if (kt < qt) load_kv(kt + 1);    // issue-early: before barrier
    __syncthreads();

    // --- S^T[key][q] = K·Q^T ---
    f32x4 s[4];
    #pragma unroll
    for (int mt = 0; mt < 4; ++mt) s[mt] = (f32x4){0.f, 0.f, 0.f, 0.f};
    __builtin_amdgcn_s_setprio(1);
    #pragma unroll
    for (int ks = 0; ks < 2; ++ks)
      #pragma unroll
      for (int mt = 0; mt < 4; ++mt) {
        bf16x8 kf = *(const bf16x8*)&Ks[buf][(mt * 16 + ln16) * XSTR + quad * 8 + ks * 32];
        s[mt] = __builtin_amdgcn_mfma_f32_16x16x32_bf16(kf, qf[ks], s[mt], 0, 0, 0);
      }
    __builtin_amdgcn_s_setprio(0);

    if (kt == qt) {              // causal mask: exp(-1e30) flushes to 0
      const int ql = wid * 16 + ln16;
      #pragma unroll
      for (int mt = 0; mt < 4; ++mt)
        #pragma unroll
        for (int reg = 0; reg < 4; ++reg)
          if (mt * 16 + quad * 4 + reg > ql) s[mt][reg] = -1e30f;
    }

    // --- static softmax: P = exp(s), no max subtraction (scores bounded) ---
    float psum = 0.f;
    #pragma unroll
    for (int mt = 0; mt < 4; ++mt) {
      float p0 = __expf(s[mt][0]), p1 = __expf(s[mt][1]);
      float p2 = __expf(s[mt][2]), p3 = __expf(s[mt][3]);
      psum += (p0 + p1) + (p2 + p3);
      ushort4 pk;
      pk.x = f2bf(p0); pk.y = f2bf(p1); pk.z = f2bf(p2); pk.w = f2bf(p3);
      *(ushort4*)&Pl[(wid * 16 + ln16) * XSTR + mt * 16 + quad * 4] = pk;
    }
    psum += __shfl_xor(psum, 16, 64);
    psum += __shfl_xor(psum, 32, 64);
    l_sum += psum;

    // --- PV: O accumulates, no rescale needed ---
    bf16x8 pa[2];
    pa[0] = *(const bf16x8*)&Pl[(wid * 16 + ln16) * XSTR + quad * 8];
    pa[1] = *(const bf16x8*)&Pl[(wid * 16 + ln16) * XSTR + quad * 8 + 32];
    __builtin_amdgcn_s_setprio(1);
    #pragma unroll
    for (int ks = 0; ks < 2; ++ks)
      #pragma unroll
      for (int nt = 0; nt < 4; ++nt) {
        bf16x8 vf = *(const bf16x8*)&Vt[buf][(nt * 16 + ln16) * XSTR + quad * 8 + ks * 32];
        O[nt] = __builtin_amdgcn_mfma_f32_16x16x32_bf16(pa[ks], vf, O[nt], 0, 0, 0);
      }
    __builtin_amdgcn_s_setprio(0);
    buf ^= 1;
  }

  float inv = 1.f / l_sum;
  #pragma unroll
  for (int reg = 0; reg < 4; ++reg) {
    float iv = __shfl(inv, quad * 4 + reg, 64);
    size_t row = (size_t)(b * T + qt * 64 + wid * 16 + quad * 4 + reg) * D;
    #pragma unroll
    for (int nt = 0; nt < 4; ++nt)
      out[row + nt * 16 + ln16] = O[nt][reg] * iv;
  }
}

// ---------------------------------------------------------------------------
extern "C" void kernel_launch(void* const* d_in, const int* in_sizes, int n_in,
                              void* d_out, int out_size, void* d_ws, size_t ws_size,
                              hipStream_t stream) {
  const float* x  = (const float*)d_in[0];
  const float* Wq = (const float*)d_in[1];
  const float* Wk = (const float*)d_in[2];
  const float* Wv = (const float*)d_in[3];
  float* outp = (float*)d_out;

  ushort* qkv = (ushort*)d_ws;                         // 12.58 MB bf16
  ushort* Wt  = qkv + (size_t)3 * B * T * D;           // +288 KB bf16

  wt_prep<<<dim3(192), dim3(256), 0, stream>>>(Wq, Wk, Wv, Wt);
  proj_mfma<<<dim3((B * T) / 64), dim3(512), 0, stream>>>(x, Wt, qkv);
  attn_mfma<<<dim3(T / 64 * B), dim3(256), 0, stream>>>(
      qkv, qkv + (size_t)B * T * D, qkv + 2 * (size_t)B * T * D, outp);
}

// Round 5
// 181.060 us; speedup vs baseline: 2.7463x; 1.0130x over previous
//
#include <hip/hip_runtime.h>
#include <cmath>

#define B 32
#define T 1024
#define CDIM 768
#define D 64
#define SCALE 0.03608439182435161f   // 1/sqrt(768), folded into Wq at prep
#define XSTR 72                      // LDS row stride (ushort): 144B, 16B-aligned

typedef short bf16x8 __attribute__((ext_vector_type(8)));
typedef float f32x4 __attribute__((ext_vector_type(4)));
typedef float f32x16 __attribute__((ext_vector_type(16)));
typedef unsigned short u16x8 __attribute__((ext_vector_type(8)));

__device__ inline ushort f2bf(float f) {
  union { float f; unsigned u; } v{f};
  unsigned r = (v.u + 0x7FFFu + ((v.u >> 16) & 1u)) >> 16;  // RNE
  return (ushort)r;
}

// ---------------------------------------------------------------------------
// Kernel 0: one-time W transpose + bf16 cvt: Wt[n=sel*64+col][k] = W_sel[k][col]
// (Wq pre-scaled by 1/sqrt(768); commutes with RoPE since rotation is linear.)
// ---------------------------------------------------------------------------
__global__ __launch_bounds__(256) void wt_prep(
    const float* __restrict__ Wq, const float* __restrict__ Wk,
    const float* __restrict__ Wv, ushort* __restrict__ Wt)
{
  const int n   = blockIdx.x;          // 0..191
  const int sel = n >> 6, col = n & 63;
  const float* W = (sel == 0) ? Wq : (sel == 1) ? Wk : Wv;
  const float sc = (sel == 0) ? SCALE : 1.f;
  for (int k = threadIdx.x; k < CDIM; k += 256)
    Wt[(size_t)n * CDIM + k] = f2bf(W[(size_t)k * D + col] * sc);
}

// ---------------------------------------------------------------------------
// Kernel 1: fused QKV projection GEMM (N=192) + RoPE, bf16 out.
// R5: SAME R0 staging/pipeline (256 thr, LDS double-buffer, one barrier/stage,
// 2-deep register prefetch issued after the barrier — R6-lesson: keep LDS;
// R3-lesson: no phase co-compilation; R4-lesson: no setprio/issue-early), but
// the MFMA core switches 16x16x32 -> 32x32x16: one MFMA = 2x FLOP for the
// same 1KB/operand LDS read. Per block-stage: 64 ds_read_b128 (was 112) and
// 48 MFMA-equiv (was 96 instrs) -> targets the measured-implied LDS/issue
// bound (R2: doubling TLP was null => throughput-bound, and FETCH shows
// x is L3-served, so not HBM).
// Wave layout: 4 waves = (mw = wid&1: 32-row M-half) x (nh = wid>>1: 96-col
// N-half of 3x 32x32 tiles). A: row=lane&31, k=(lane>>5)*8+e. B: col=lane&31,
// same k. C/D: col=lane&31, row=(reg&3)+8*(reg>>2)+4*(lane>>5) [m74/m101].
// ---------------------------------------------------------------------------
__global__ __launch_bounds__(256) void proj_mfma(
    const float* __restrict__ x,
    const ushort* __restrict__ Wt,
    ushort* __restrict__ qkv)          // [3][B*T][D] bf16
{
  const int t    = threadIdx.x;        // 0..255
  const int lane = t & 63;
  const int wid  = t >> 6;             // 0..3
  const int ln32 = lane & 31;
  const int half = lane >> 5;          // 0/1
  const int mw   = wid & 1;            // M-half (32 rows)
  const int nh   = wid >> 1;           // N-half (96 cols = 3 tiles)
  const int row0 = blockIdx.x * 64;

  __shared__ ushort Xs[2][64 * XSTR];    // 2 x 9216 B
  __shared__ ushort Ws[2][192 * XSTR];   // 2 x 27648 B (73.7 KB -> 2 blk/CU)

  f32x16 acc[3];
  #pragma unroll
  for (int nt = 0; nt < 3; ++nt)
    #pragma unroll
    for (int rg = 0; rg < 16; ++rg) acc[nt][rg] = 0.f;

  float4 xp[2][4];   // 2-deep x prefetch (fp32, cvt at LDS-write time)
  u16x8  wp[2][6];   // 2-deep Wt prefetch (already bf16)

  auto load_stage = [&](int s, int set) {
    const int k0 = s * 64;
    #pragma unroll
    for (int it = 0; it < 4; ++it) {
      int slot = it * 256 + t, row = slot >> 4, kq = slot & 15;
      xp[set][it] = *(const float4*)(x + (size_t)(row0 + row) * CDIM + k0 + kq * 4);
    }
    #pragma unroll
    for (int it = 0; it < 6; ++it) {
      int slot = it * 256 + t, n = slot >> 3, kb = slot & 7;
      wp[set][it] = *(const u16x8*)(Wt + (size_t)n * CDIM + k0 + kb * 8);
    }
  };

  load_stage(0, 0);
  load_stage(1, 1);
  int buf = 0;
  for (int s = 0; s < CDIM / 64; ++s) {
    const int set = s & 1;
    #pragma unroll
    for (int it = 0; it < 4; ++it) {
      int slot = it * 256 + t, row = slot >> 4, kq = slot & 15;
      ushort4 bv;
      bv.x = f2bf(xp[set][it].x); bv.y = f2bf(xp[set][it].y);
      bv.z = f2bf(xp[set][it].z); bv.w = f2bf(xp[set][it].w);
      *(ushort4*)&Xs[buf][row * XSTR + kq * 4] = bv;
    }
    #pragma unroll
    for (int it = 0; it < 6; ++it) {
      int slot = it * 256 + t, n = slot >> 3, kb = slot & 7;
      *(u16x8*)&Ws[buf][n * XSTR + kb * 8] = wp[set][it];
    }
    __syncthreads();
    if (s + 2 < CDIM / 64) load_stage(s + 2, set);

    #pragma unroll
    for (int kk = 0; kk < 4; ++kk) {           // 4 x K=16 steps per stage
      bf16x8 a = *(const bf16x8*)&Xs[buf][(mw * 32 + ln32) * XSTR + kk * 16 + half * 8];
      #pragma unroll
      for (int nt = 0; nt < 3; ++nt) {
        bf16x8 bb = *(const bf16x8*)&Ws[buf][(nh * 96 + nt * 32 + ln32) * XSTR + kk * 16 + half * 8];
        acc[nt] = __builtin_amdgcn_mfma_f32_32x32x16_bf16(a, bb, acc[nt], 0, 0, 0);
      }
    }
    buf ^= 1;
  }

  // epilogue: 32x32 C/D: col=lane&31, row=(reg&3)+8*(reg>>2)+4*half.
  // n = nh*96 + nt*32 + col -> sel = n>>6 (uniform per tile), d = n&63.
  // RoPE partner d^1 = col^1 -> lane^1 (same half, same reg/rowg).
  #pragma unroll
  for (int nt = 0; nt < 3; ++nt) {
    const int n   = nh * 96 + nt * 32 + ln32;
    const int sel = n >> 6;
    const int d   = n & 63;
    ushort* outb = qkv + (size_t)sel * (B * T * D);
    if (sel < 2) {
      const float freq = __expf((float)(d & 62) * (-0.14391156855801f));
      const float sgn  = (d & 1) ? 1.f : -1.f;
      #pragma unroll
      for (int reg = 0; reg < 16; ++reg) {
        int rowg = row0 + mw * 32 + (reg & 3) + 8 * (reg >> 2) + 4 * half;
        float sv, cv;
        __sincosf((float)(rowg & (T - 1)) * freq, &sv, &cv);
        float val = acc[nt][reg];
        float partner = __shfl_xor(val, 1, 64);
        outb[(size_t)rowg * D + d] = f2bf(fmaf(sgn * partner, sv, val * cv));
      }
    } else {
      #pragma unroll
      for (int reg = 0; reg < 16; ++reg) {
        int rowg = row0 + mw * 32 + (reg & 3) + 8 * (reg >> 2) + 4 * half;
        outb[(size_t)rowg * D + d] = f2bf(acc[nt][reg]);
      }
    }
  }
}

// ---------------------------------------------------------------------------
// Kernel 2: causal flash attention, bf16 MFMA, STATIC softmax (m == 0).
// EXACT R1 body (best measured: 179.9 us total). R4's setprio + issue-early
// regressed ~3.5 us -> reverted.
// Scores statically bounded -> no online-max machinery (shift-invariant).
// S^T = K·Q^T; double-buffered Ks/Vt; one barrier per kt.
// R1 remap: b = l&31 (XCD = b%8 -> K/V L2-resident), qt = r<8 ? r : 23-r
// (cohabitant qt's sum to 15 -> every CU gets 17 kt-units).
// ---------------------------------------------------------------------------
__global__ __launch_bounds__(256) void attn_mfma(
    const ushort* __restrict__ qg,
    const ushort* __restrict__ kg,
    const ushort* __restrict__ vg,
    float* __restrict__ out)
{
  const int t    = threadIdx.x;
  const int lane = t & 63;
  const int wid  = t >> 6;
  const int ln16 = lane & 15;
  const int quad = lane >> 4;
  const int l    = (int)blockIdx.x;      // 0..511
  const int b    = l & 31;
  const int r    = l >> 5;
  const int qt   = (r < 8) ? r : 23 - r;

  __shared__ ushort Ks[2][64 * XSTR];
  __shared__ ushort Vt[2][64 * XSTR];
  __shared__ ushort Pl[64 * XSTR];         // wave-private rows

  bf16x8 qf[2];
  {
    const ushort* qrow = qg + (size_t)(b * T + qt * 64 + wid * 16 + ln16) * D;
    qf[0] = *(const bf16x8*)(qrow + quad * 8);
    qf[1] = *(const bf16x8*)(qrow + quad * 8 + 32);
  }

  f32x4 O[4];
  #pragma unroll
  for (int nt = 0; nt < 4; ++nt) O[nt] = (f32x4){0.f, 0.f, 0.f, 0.f};
  float l_sum = 0.f;

  const int kb = t & 15, db = t >> 4;
  const int d0 = db * 4, kk0 = kb * 4;

  u16x8  kp[2];
  ushort4 vp[4];
  auto load_kv = [&](int kt) {
    #pragma unroll
    for (int i = 0; i < 2; ++i) {
      int slot = i * 256 + t, row = slot >> 3, dblk = slot & 7;
      kp[i] = *(const u16x8*)(kg + (size_t)(b * T + kt * 64 + row) * D + dblk * 8);
    }
    #pragma unroll
    for (int i = 0; i < 4; ++i)
      vp[i] = *(const ushort4*)(vg + (size_t)(b * T + kt * 64 + kk0 + i) * D + d0);
  };

  load_kv(0);
  int buf = 0;
  for (int kt = 0; kt <= qt; ++kt) {
    #pragma unroll
    for (int i = 0; i < 2; ++i) {
      int slot = i * 256 + t, row = slot >> 3, dblk = slot & 7;
      *(u16x8*)&Ks[buf][row * XSTR + dblk * 8] = kp[i];
    }
    const ushort* vpe = (const ushort*)vp;
    #pragma unroll
    for (int j = 0; j < 4; ++j) {
      ushort4 c;
      c.x = vpe[0 * 4 + j]; c.y = vpe[1 * 4 + j];
      c.z = vpe[2 * 4 + j]; c.w = vpe[3 * 4 + j];
      *(ushort4*)&Vt[buf][(d0 + j) * XSTR + kk0] = c;
    }
    __syncthreads();
    if (kt < qt) load_kv(kt + 1);    // in flight through this iter's compute

    // --- S^T[key][q] = K·Q^T ---
    f32x4 s[4];
    #pragma unroll
    for (int mt = 0; mt < 4; ++mt) s[mt] = (f32x4){0.f, 0.f, 0.f, 0.f};
    #pragma unroll
    for (int ks = 0; ks < 2; ++ks)
      #pragma unroll
      for (int mt = 0; mt < 4; ++mt) {
        bf16x8 kf = *(const bf16x8*)&Ks[buf][(mt * 16 + ln16) * XSTR + quad * 8 + ks * 32];
        s[mt] = __builtin_amdgcn_mfma_f32_16x16x32_bf16(kf, qf[ks], s[mt], 0, 0, 0);
      }

    if (kt == qt) {              // causal mask: exp(-1e30) flushes to 0
      const int ql = wid * 16 + ln16;
      #pragma unroll
      for (int mt = 0; mt < 4; ++mt)
        #pragma unroll
        for (int reg = 0; reg < 4; ++reg)
          if (mt * 16 + quad * 4 + reg > ql) s[mt][reg] = -1e30f;
    }

    // --- static softmax: P = exp(s), no max subtraction (scores bounded) ---
    float psum = 0.f;
    #pragma unroll
    for (int mt = 0; mt < 4; ++mt) {
      float p0 = __expf(s[mt][0]), p1 = __expf(s[mt][1]);
      float p2 = __expf(s[mt][2]), p3 = __expf(s[mt][3]);
      psum += (p0 + p1) + (p2 + p3);
      ushort4 pk;
      pk.x = f2bf(p0); pk.y = f2bf(p1); pk.z = f2bf(p2); pk.w = f2bf(p3);
      *(ushort4*)&Pl[(wid * 16 + ln16) * XSTR + mt * 16 + quad * 4] = pk;
    }
    psum += __shfl_xor(psum, 16, 64);
    psum += __shfl_xor(psum, 32, 64);
    l_sum += psum;

    // --- PV: O accumulates, no rescale needed ---
    bf16x8 pa[2];
    pa[0] = *(const bf16x8*)&Pl[(wid * 16 + ln16) * XSTR + quad * 8];
    pa[1] = *(const bf16x8*)&Pl[(wid * 16 + ln16) * XSTR + quad * 8 + 32];
    #pragma unroll
    for (int ks = 0; ks < 2; ++ks)
      #pragma unroll
      for (int nt = 0; nt < 4; ++nt) {
        bf16x8 vf = *(const bf16x8*)&Vt[buf][(nt * 16 + ln16) * XSTR + quad * 8 + ks * 32];
        O[nt] = __builtin_amdgcn_mfma_f32_16x16x32_bf16(pa[ks], vf, O[nt], 0, 0, 0);
      }
    buf ^= 1;
  }

  float inv = 1.f / l_sum;
  #pragma unroll
  for (int reg = 0; reg < 4; ++reg) {
    float iv = __shfl(inv, quad * 4 + reg, 64);
    size_t row = (size_t)(b * T + qt * 64 + wid * 16 + quad * 4 + reg) * D;
    #pragma unroll
    for (int nt = 0; nt < 4; ++nt)
      out[row + nt * 16 + ln16] = O[nt][reg] * iv;
  }
}

// ---------------------------------------------------------------------------
extern "C" void kernel_launch(void* const* d_in, const int* in_sizes, int n_in,
                              void* d_out, int out_size, void* d_ws, size_t ws_size,
                              hipStream_t stream) {
  const float* x  = (const float*)d_in[0];
  const float* Wq = (const float*)d_in[1];
  const float* Wk = (const float*)d_in[2];
  const float* Wv = (const float*)d_in[3];
  float* outp = (float*)d_out;

  ushort* qkv = (ushort*)d_ws;                         // 12.58 MB bf16
  ushort* Wt  = qkv + (size_t)3 * B * T * D;           // +288 KB bf16

  wt_prep<<<dim3(192), dim3(256), 0, stream>>>(Wq, Wk, Wv, Wt);
  proj_mfma<<<dim3((B * T) / 64), dim3(256), 0, stream>>>(x, Wt, qkv);
  attn_mfma<<<dim3(T / 64 * B), dim3(256), 0, stream>>>(
      qkv, qkv + (size_t)B * T * D, qkv + 2 * (size_t)B * T * D, outp);
}